// Round 6
// baseline (486.574 us; speedup 1.0000x reference)
//
#include <hip/hip_runtime.h>
#include <hip/hip_bf16.h>
#include <cmath>

#define Bz 32
#define Tz 2048
#define Vz 32
#define Cz 64   // chunks per batch
#define Lz 32   // steps per chunk
#define WPB 4   // waves (chunks) per block
#define BLK_PER_BATCH (Cz / WPB)   // 16

typedef short short8 __attribute__((ext_vector_type(8)));
typedef float f32x16 __attribute__((ext_vector_type(16)));
typedef float f32x4  __attribute__((ext_vector_type(4)));

static __device__ __forceinline__ unsigned short f2bf(float x) {
    unsigned u = __builtin_bit_cast(unsigned, x);
    u += 0x7FFFu + ((u >> 16) & 1u);          // RNE
    return (unsigned short)(u >> 16);
}

static __device__ __forceinline__ void gl_lds16(const float* g, float* l) {
    __builtin_amdgcn_global_load_lds(
        (const __attribute__((address_space(1))) void*)g,
        (__attribute__((address_space(3))) void*)l, 16, 0, 0);
}

// ---- combine helpers (1 wave, lane l owns alpha column l&31, dup across halves) ----
#define LOADQ(buf, chunk)                                                  \
    do { if ((chunk) < Cz) {                                               \
        const float* Pn = Pb + (size_t)(chunk) * 1024;                     \
        _Pragma("unroll")                                                  \
        for (int ii = 0; ii < 16; ++ii) buf[ii] = Pn[(hh + ii) * 32 + j];  \
    } } while (0)

#define PROCQ(buf)                                                         \
    do {                                                                   \
        float x[16];                                                       \
        _Pragma("unroll")                                                  \
        for (int ii = 0; ii < 16; ++ii)                                    \
            x[ii] = __shfl(al, hh + ii, 64) + buf[ii];                     \
        float u0 = fmaxf(x[0], x[1]),  u1 = fmaxf(x[2], x[3]);             \
        float u2 = fmaxf(x[4], x[5]),  u3 = fmaxf(x[6], x[7]);             \
        float u4 = fmaxf(x[8], x[9]),  u5 = fmaxf(x[10], x[11]);           \
        float u6 = fmaxf(x[12], x[13]), u7 = fmaxf(x[14], x[15]);          \
        u0 = fmaxf(u0, u1); u2 = fmaxf(u2, u3);                            \
        u4 = fmaxf(u4, u5); u6 = fmaxf(u6, u7);                            \
        u0 = fmaxf(u0, u2); u4 = fmaxf(u4, u6);                            \
        float mx = fmaxf(u0, u4);                                          \
        mx = fmaxf(mx, __shfl_xor(mx, 32, 64));                            \
        float e[16];                                                       \
        _Pragma("unroll")                                                  \
        for (int ii = 0; ii < 16; ++ii) e[ii] = __expf(x[ii] - mx);        \
        float s0 = e[0] + e[1],   s1 = e[2] + e[3];                        \
        float s2 = e[4] + e[5],   s3 = e[6] + e[7];                        \
        float s4 = e[8] + e[9],   s5 = e[10] + e[11];                      \
        float s6 = e[12] + e[13], s7 = e[14] + e[15];                      \
        s0 += s1; s2 += s3; s4 += s5; s6 += s7;                            \
        s0 += s2; s4 += s6;                                                \
        float s = s0 + s4;                                                 \
        s += __shfl_xor(s, 32, 64);                                        \
        al = mx + __logf(s);                                               \
    } while (0)

// ---------------- Fused kernel: chunk semiring products + last-block combine ----------------
// Per wave: one 32-step chunk. State E (32x32 col-scaled linear, MFMA C-layout regs),
// c_j col log-scales. Step: M[k,j]=c_k+s_t[k,j]+trans[k,j]; d_j=colmax; G=exp(M-d);
// E@=G via 2x mfma_32x32x16_bf16; col-renorm. Operand k-slot mapping is a free
// bijection (cancels between A and B); only C/D layout must be exact (m74/m101).
// Tail: 16th arriving block of each batch combines its 64 chunk matrices (1 wave).
__global__ void __launch_bounds__(256) crf_fused(
    const float* __restrict__ inputs, const float* __restrict__ trans,
    const int* __restrict__ targets, const float* __restrict__ initial,
    const float* __restrict__ fin, float* __restrict__ Pout,
    float* __restrict__ numpart, int* __restrict__ cnt, float* __restrict__ out)
{
    __shared__ __align__(16) float trans_lds[1024];
    __shared__ __align__(16) float sbuf[WPB][4 * 1024];        // depth-3 pipeline (4 bufs)
    __shared__ __align__(16) unsigned short elds[WPB][32 * 40]; // E bf16, pitch 40
    __shared__ __align__(16) float cbuf[WPB][32];
    __shared__ int lastflag;

    const int tid  = threadIdx.x;
    const int lane = tid & 63;
    const int wid  = tid >> 6;
    const int gid  = __builtin_amdgcn_readfirstlane(blockIdx.x * WPB + wid);
    const int b    = gid >> 6;          // batch (same for all 4 waves)
    const int c    = gid & (Cz - 1);

    const int h = lane >> 5;
    const int j = lane & 31;            // B-frag col / A-frag row / C col
    const int kbase = 8 * h;

    // transition at this lane's (k,j) fragment slots — constant in regs
    float tr[16];
#pragma unroll
    for (int e = 0; e < 8; ++e) {
        tr[e]     = trans[(kbase + e) * Vz + j];
        tr[8 + e] = trans[(16 + kbase + e) * Vz + j];
    }
    ((float4*)trans_lds)[tid] = ((const float4*)trans)[tid];
    __syncthreads();

    const float* src = inputs + ((size_t)b * Tz + (size_t)c * Lz) * (Vz * Vz);
    const int*   tgb = targets + b * (Tz + 1) + c * Lz;
    int tgv = (lane < Lz + 1) ? tgb[lane] : 0;

    // ---- prologue: stage s_0..s_2 (12 loads) ----
    float* sw = sbuf[wid];
#pragma unroll
    for (int pt = 0; pt < 3; ++pt) {
        const float* g = src + pt * 1024 + lane * 4;
#pragma unroll
        for (int q = 0; q < 4; ++q) gl_lds16(g + q * 256, sw + pt * 1024 + q * 256);
    }

    f32x16 p;
    float cj = 0.f, epart = 0.f;
    float ckr[16];
#pragma unroll
    for (int e = 0; e < 16; ++e) ckr[e] = 0.f;

    for (int t = 0; t < Lz; ++t) {
        if (t + 3 < Lz) {   // prefetch depth 3
            const float* g = src + (t + 3) * 1024 + lane * 4;
            float* dst = sw + ((t + 3) & 3) * 1024;
#pragma unroll
            for (int q = 0; q < 4; ++q) gl_lds16(g + q * 256, dst + q * 256);
        }
        // counted vmcnt: exactly 4 global_load_lds per staged step
        const int rem = Lz - 1 - t;
        if (rem >= 3)      { asm volatile("s_waitcnt vmcnt(12)" ::: "memory"); }
        else if (rem == 2) { asm volatile("s_waitcnt vmcnt(8)"  ::: "memory"); }
        else if (rem == 1) { asm volatile("s_waitcnt vmcnt(4)"  ::: "memory"); }
        else               { asm volatile("s_waitcnt vmcnt(0)"  ::: "memory"); }
        __builtin_amdgcn_sched_barrier(0);

        const float* sb = sw + (t & 3) * 1024;

        // numerator emit+trans along target path — broadcast LDS read
        {
            int yp = __shfl(tgv, t, 64);
            int yn = __shfl(tgv, t + 1, 64);
            int eidx = yp * Vz + yn;
            epart += sb[eidx] + trans_lds[eidx];
        }

        float m[16];
#pragma unroll
        for (int e = 0; e < 8; ++e) {
            m[e]     = sb[(kbase + e) * Vz + j]      + tr[e]     + ckr[e];
            m[8 + e] = sb[(16 + kbase + e) * Vz + j] + tr[8 + e] + ckr[8 + e];
        }
        float d = m[0];
#pragma unroll
        for (int e = 1; e < 16; ++e) d = fmaxf(d, m[e]);
        d = fmaxf(d, __shfl_xor(d, 32, 64));   // lanes l, l^32 share column j

        short8 B1, B2;
#pragma unroll
        for (int e = 0; e < 8; ++e) {
            B1[e] = (short)f2bf(__expf(m[e] - d));
            B2[e] = (short)f2bf(__expf(m[8 + e] - d));
        }

        short8 A1, A2;   // E fragments: row = j, k = kbase+e (+16)
        if (t == 0) {    // E = I exactly
#pragma unroll
            for (int e = 0; e < 8; ++e) {
                A1[e] = (short)((kbase + e == j) ? 0x3F80 : 0);
                A2[e] = (short)((16 + kbase + e == j) ? 0x3F80 : 0);
            }
        } else {
            const unsigned short* ew = elds[wid] + j * 40;
            A1 = *(const short8*)(ew + kbase);
            A2 = *(const short8*)(ew + 16 + kbase);
        }

        f32x16 z = {};
        p = __builtin_amdgcn_mfma_f32_32x32x16_bf16(A1, B1, z, 0, 0, 0);
        p = __builtin_amdgcn_mfma_f32_32x32x16_bf16(A2, B2, p, 0, 0, 0);

        // column renorm (colmax in [1,32])
        float mj = p[0];
#pragma unroll
        for (int r = 1; r < 16; ++r) mj = fmaxf(mj, p[r]);
        mj = fmaxf(mj, __shfl_xor(mj, 32, 64));
        float inv = 1.0f / mj;
#pragma unroll
        for (int r = 0; r < 16; ++r) p[r] *= inv;
        cj = d + __logf(mj);

        unsigned short* ew = elds[wid];
#pragma unroll
        for (int r = 0; r < 16; ++r) {
            const int row = (r & 3) + 8 * (r >> 2) + 4 * h;   // C/D layout (m74/m101)
            ew[row * 40 + j] = f2bf(p[r]);
        }
        if (lane < 32) cbuf[wid][j] = cj;
        {
            const float* cb = cbuf[wid];
            f32x4 c0 = *(const f32x4*)(cb + kbase);
            f32x4 c1 = *(const f32x4*)(cb + kbase + 4);
            f32x4 c2 = *(const f32x4*)(cb + 16 + kbase);
            f32x4 c3 = *(const f32x4*)(cb + 16 + kbase + 4);
#pragma unroll
            for (int v = 0; v < 4; ++v) {
                ckr[v] = c0[v]; ckr[4 + v] = c1[v];
                ckr[8 + v] = c2[v]; ckr[12 + v] = c3[v];
            }
        }
    }

    // write P = c_j + log E, and numerator partial
    float* Pc = Pout + (size_t)gid * 1024;
#pragma unroll
    for (int r = 0; r < 16; ++r) {
        const int row = (r & 3) + 8 * (r >> 2) + 4 * h;
        Pc[row * Vz + j] = cj + __logf(p[r]);
    }
    if (lane == 0) numpart[gid] = epart;

    // ---- last-block-per-batch combine tail ----
    __threadfence();                 // release: every thread's P/numpart writes
    __syncthreads();                 // all fences done before the block's atomic
    if (tid == 0) lastflag = (atomicAdd(&cnt[b], 1) == BLK_PER_BATCH - 1);
    __syncthreads();
    if (!lastflag || tid >= 64) return;
    __threadfence();                 // acquire: discard stale cached P lines

    const int hh = h * 16;           // lane = tid (single wave)
    const float* Pb = Pout + (size_t)b * Cz * 1024;
    float al = initial[j];

    float q0[16], q1[16], q2[16], q3[16];
    LOADQ(q0, 0); LOADQ(q1, 1); LOADQ(q2, 2); LOADQ(q3, 3);
    for (int cc = 0; cc < Cz; cc += 4) {
        PROCQ(q0); LOADQ(q0, cc + 4);
        PROCQ(q1); LOADQ(q1, cc + 5);
        PROCQ(q2); LOADQ(q2, cc + 6);
        PROCQ(q3); LOADQ(q3, cc + 7);
    }

    // denom = lse_j(alpha[j]+final[j]); mask dup half, cross-half reduce first
    float mm = (h == 0) ? (al + fin[j]) : -INFINITY;
    float ss = 1.f;
#pragma unroll
    for (int off = 32; off >= 1; off >>= 1) {
        float om = __shfl_xor(mm, off, 64);
        float os = __shfl_xor(ss, off, 64);
        float nm = fmaxf(mm, om);
        ss = ss * __expf(mm - nm) + os * __expf(om - nm);
        mm = nm;
    }
    float denom = mm + __logf(ss);

    float np = numpart[b * Cz + lane];   // Cz == 64 lanes
#pragma unroll
    for (int off = 32; off >= 1; off >>= 1) np += __shfl_xor(np, off, 64);

    if (lane == 0) {
        const int* tg = targets + b * (Tz + 1);
        out[b] = np + initial[tg[0]] + fin[tg[Tz]] - denom;
    }
}

extern "C" void kernel_launch(void* const* d_in, const int* in_sizes, int n_in,
                              void* d_out, int out_size, void* d_ws, size_t ws_size,
                              hipStream_t stream) {
    const float* inputs  = (const float*)d_in[0];
    const float* trans   = (const float*)d_in[1];
    const float* initial = (const float*)d_in[2];
    const float* fin     = (const float*)d_in[3];
    const int*   targets = (const int*)d_in[4];

    float* Pout    = (float*)d_ws;                       // 2048*1024 fp32 = 8 MB
    float* numpart = Pout + (size_t)Bz * Cz * 1024;      // + 8 KB
    int*   cnt     = (int*)(numpart + Bz * Cz);          // + 128 B

    hipMemsetAsync(cnt, 0, Bz * sizeof(int), stream);    // zero per-batch arrival counters
    hipLaunchKernelGGL(crf_fused, dim3(Bz * Cz / WPB), dim3(256), 0, stream,
                       inputs, trans, targets, initial, fin,
                       Pout, numpart, cnt, (float*)d_out);
}

// Round 9
// 400.095 us; speedup vs baseline: 1.2161x; 1.2161x over previous
//
#include <hip/hip_runtime.h>
#include <cmath>

#define Bz 32
#define Tz 2048
#define Vz 32
#define Cz 64   // chunks per batch
#define Lz 32   // steps per chunk
#define WPB 4   // waves (chunks) per block

typedef short short8 __attribute__((ext_vector_type(8)));
typedef float f32x16 __attribute__((ext_vector_type(16)));
typedef unsigned int u32x4 __attribute__((ext_vector_type(4)));

static __device__ __forceinline__ unsigned f2bf_u(float x) {
    unsigned u = __builtin_bit_cast(unsigned, x);
    u += 0x7FFFu + ((u >> 16) & 1u);          // RNE
    return u >> 16;
}
static __device__ __forceinline__ unsigned cvtpk(float lo, float hi) {
    unsigned r;
    asm("v_cvt_pk_bf16_f32 %0, %1, %2" : "=v"(r) : "v"(lo), "v"(hi));
    return r;
}

// tree max of 16 (dep depth 4)
#define WMAX16(dst, arr) do {                                               \
    float w0=fmaxf(arr[0],arr[1]),  w1=fmaxf(arr[2],arr[3]);                \
    float w2=fmaxf(arr[4],arr[5]),  w3=fmaxf(arr[6],arr[7]);                \
    float w4=fmaxf(arr[8],arr[9]),  w5=fmaxf(arr[10],arr[11]);              \
    float w6=fmaxf(arr[12],arr[13]),w7=fmaxf(arr[14],arr[15]);              \
    w0=fmaxf(w0,w1); w2=fmaxf(w2,w3); w4=fmaxf(w4,w5); w6=fmaxf(w6,w7);     \
    w0=fmaxf(w0,w2); w4=fmaxf(w4,w6); dst = fmaxf(w0,w4);                   \
} while (0)

#define WAVEMAXF(v) do {                                                    \
    v = fmaxf(v, __shfl_xor(v, 1, 64));                                     \
    v = fmaxf(v, __shfl_xor(v, 2, 64));                                     \
    v = fmaxf(v, __shfl_xor(v, 4, 64));                                     \
    v = fmaxf(v, __shfl_xor(v, 8, 64));                                     \
    v = fmaxf(v, __shfl_xor(v, 16, 64));                                    \
    v = fmaxf(v, __shfl_xor(v, 32, 64));                                    \
} while (0)

// ---------------- Kernel A: per-(batch,chunk) semiring product, all-register ----------------
// State S = E^T in MFMA C-layout regs (f32x16 p), single wave-global log-scale gam.
// Step: x[k,c]=s_t[k,c]+tr[k,c]; d=wavemax(x); A-frag=exp(x-d) (=G^T; k-slot bijection
// cancels between A and B); B-frag of S from p: cvt_pk pack, shfl_xor(32), static
// selects per inverse C-layout (lane=c+32*((row>>2)&1), reg=(row&3)+4*(row>>3);
// C/D layout HW-verified m74/m101). p=mfma(A1,B1,0); p=mfma(A2,B2,p).
// Renorm (wave-max scale -> gam) every 4th step only: d-shift keeps G<=1, so
// growth <= 32^4 per quad, decay bounded — far inside f32 range.
__global__ void __launch_bounds__(256, 2) crf_chunks(
    const float* __restrict__ inputs, const float* __restrict__ trans,
    const int* __restrict__ targets, float* __restrict__ Pout,
    float* __restrict__ numpart)
{
    __shared__ __align__(16) float trans_lds[1024];

    const int tid  = threadIdx.x;
    const int lane = tid & 63;
    const int wid  = tid >> 6;
    const int gid  = blockIdx.x * WPB + wid;
    const int b    = gid >> 6;          // / Cz
    const int c    = gid & (Cz - 1);

    const int H   = lane >> 5;
    const int col = lane & 31;          // A row / B col / C col
    const int kb1 = 8 * H;
    const int kb2 = 16 + 8 * H;

    // transition at this lane's 16 (k,col) fragment slots — constant in regs
    float tr[16];
#pragma unroll
    for (int e = 0; e < 8; ++e) {
        tr[e]     = trans[(kb1 + e) * Vz + col];
        tr[8 + e] = trans[(kb2 + e) * Vz + col];
    }
    ((float4*)trans_lds)[tid] = ((const float4*)trans)[tid];
    __syncthreads();

    const float* src = inputs + ((size_t)b * Tz + (size_t)c * Lz) * 1024;

    // numerator: lane t<32 owns step t (fully parallel, off the critical path)
    const int* tgb = targets + b * (Tz + 1) + c * Lz;
    int tg  = (lane <= Lz) ? tgb[lane] : 0;
    int tgn = __shfl(tg, lane + 1, 64);
    float epart = 0.f;
    if (lane < Lz) {
        int eidx = tg * Vz + tgn;
        epart = src[lane * 1024 + eidx] + trans_lds[eidx];
    }

    // S = I in C-layout
    f32x16 p;
#pragma unroll
    for (int r = 0; r < 16; ++r)
        p[r] = (((r & 3) + 8 * (r >> 2) + 4 * H) == col) ? 1.f : 0.f;
    float gam = 0.f;

#define LOADM(buf, t) do {                                                  \
    const float* s_ = src + (size_t)(t) * 1024;                             \
    _Pragma("unroll")                                                       \
    for (int e = 0; e < 8; ++e) {                                           \
        buf[e]     = s_[(kb1 + e) * Vz + col];                              \
        buf[8 + e] = s_[(kb2 + e) * Vz + col];                              \
    } } while (0)

    float mA[16], mB[16], mC[16], mD[16];
    LOADM(mA, 0); LOADM(mB, 1); LOADM(mC, 2); LOADM(mD, 3);

#define STEP(buf, t, RN) do {                                               \
    float x[16];                                                            \
    _Pragma("unroll")                                                       \
    for (int i_ = 0; i_ < 16; ++i_) x[i_] = buf[i_] + tr[i_];               \
    if ((t) + 4 < Lz) LOADM(buf, (t) + 4);   /* depth-4 reg prefetch */     \
    float d; WMAX16(d, x); WAVEMAXF(d);                                     \
    /* A-frags: exp(x-d), off the p-critical-path */                        \
    u32x4 a1u, a2u;                                                         \
    _Pragma("unroll")                                                       \
    for (int e = 0; e < 4; ++e) {                                           \
        a1u[e] = f2bf_u(__expf(x[2*e]     - d)) |                           \
                 (f2bf_u(__expf(x[2*e+1]   - d)) << 16);                    \
        a2u[e] = f2bf_u(__expf(x[8+2*e]   - d)) |                           \
                 (f2bf_u(__expf(x[8+2*e+1] - d)) << 16);                    \
    }                                                                       \
    /* B-frags from S: cvt_pk pack, cross-half swap, static select */       \
    unsigned pk[8], qk[8];                                                  \
    _Pragma("unroll")                                                       \
    for (int i_ = 0; i_ < 8; ++i_) pk[i_] = cvtpk(p[2*i_], p[2*i_+1]);      \
    _Pragma("unroll")                                                       \
    for (int i_ = 0; i_ < 8; ++i_) qk[i_] = __shfl_xor(pk[i_], 32, 64);     \
    u32x4 b1u, b2u;                                                         \
    b1u[0] = H ? qk[2] : pk[0];  b1u[1] = H ? qk[3] : pk[1];                \
    b1u[2] = H ? pk[2] : qk[0];  b1u[3] = H ? pk[3] : qk[1];                \
    b2u[0] = H ? qk[6] : pk[4];  b2u[1] = H ? qk[7] : pk[5];                \
    b2u[2] = H ? pk[6] : qk[4];  b2u[3] = H ? pk[7] : qk[5];                \
    short8 A1 = __builtin_bit_cast(short8, a1u);                            \
    short8 A2 = __builtin_bit_cast(short8, a2u);                            \
    short8 B1 = __builtin_bit_cast(short8, b1u);                            \
    short8 B2 = __builtin_bit_cast(short8, b2u);                            \
    f32x16 z = {};                                                          \
    p = __builtin_amdgcn_mfma_f32_32x32x16_bf16(A1, B1, z, 0, 0, 0);        \
    p = __builtin_amdgcn_mfma_f32_32x32x16_bf16(A2, B2, p, 0, 0, 0);        \
    gam += d;                                                               \
    if (RN) {                                                               \
        float ms; WMAX16(ms, p); WAVEMAXF(ms);                              \
        float inv = 1.0f / ms;                                              \
        _Pragma("unroll")                                                   \
        for (int r_ = 0; r_ < 16; ++r_) p[r_] *= inv;                       \
        gam += __logf(ms);                                                  \
    }                                                                       \
} while (0)

    for (int t = 0; t < Lz; t += 4) {
        STEP(mA, t, 0); STEP(mB, t + 1, 0); STEP(mC, t + 2, 0); STEP(mD, t + 3, 1);
    }

    // Pout_chunk[j*32+k] = gam + log S[j,k]  (= logP[k -> j]); log(0)=-inf ok downstream
    float* Pc = Pout + (size_t)gid * 1024;
#pragma unroll
    for (int r = 0; r < 16; ++r) {
        int row = (r & 3) + 8 * (r >> 2) + 4 * H;
        Pc[row * Vz + col] = gam + __logf(p[r]);
    }
#pragma unroll
    for (int off = 32; off >= 1; off >>= 1) epart += __shfl_xor(epart, off, 64);
    if (lane == 0) numpart[gid] = epart;
}

// ---------------- Kernel B: sequential combine (1 wave/batch) ----------------
// alpha'_j = lse_k(alpha_k + Pc[j*32+k]); lane owns j=lane&31 (dup across halves),
// k-range split by half. Depth-4 prefetch, float4 loads, tree reductions.
#define LOADQ(buf, chunk) do { if ((chunk) < Cz) {                          \
    const float4* Pn = (const float4*)(Pb + (size_t)(chunk) * 1024 + j * 32 + hh); \
    float4 v0 = Pn[0], v1 = Pn[1], v2 = Pn[2], v3 = Pn[3];                  \
    buf[0]=v0.x; buf[1]=v0.y; buf[2]=v0.z; buf[3]=v0.w;                     \
    buf[4]=v1.x; buf[5]=v1.y; buf[6]=v1.z; buf[7]=v1.w;                     \
    buf[8]=v2.x; buf[9]=v2.y; buf[10]=v2.z; buf[11]=v2.w;                   \
    buf[12]=v3.x; buf[13]=v3.y; buf[14]=v3.z; buf[15]=v3.w;                 \
} } while (0)

#define PROCQ(buf) do {                                                     \
    float x[16];                                                            \
    _Pragma("unroll")                                                       \
    for (int ii = 0; ii < 16; ++ii)                                         \
        x[ii] = __shfl(al, hh + ii, 64) + buf[ii];                          \
    float mx; WMAX16(mx, x);                                                \
    mx = fmaxf(mx, __shfl_xor(mx, 32, 64));                                 \
    float e[16];                                                            \
    _Pragma("unroll")                                                       \
    for (int ii = 0; ii < 16; ++ii) e[ii] = __expf(x[ii] - mx);             \
    float s0=e[0]+e[1],   s1=e[2]+e[3],   s2=e[4]+e[5],   s3=e[6]+e[7];     \
    float s4=e[8]+e[9],   s5=e[10]+e[11], s6=e[12]+e[13], s7=e[14]+e[15];   \
    s0+=s1; s2+=s3; s4+=s5; s6+=s7; s0+=s2; s4+=s6;                         \
    float s = s0 + s4;                                                      \
    s += __shfl_xor(s, 32, 64);                                             \
    al = mx + __logf(s);                                                    \
} while (0)

__global__ void __launch_bounds__(64) crf_combine(
    const float* __restrict__ Pout, const float* __restrict__ numpart,
    const float* __restrict__ initial, const float* __restrict__ fin,
    const int* __restrict__ targets, float* __restrict__ out)
{
    const int lane = threadIdx.x;
    const int b = blockIdx.x;
    const int h = lane >> 5;
    const int j = lane & 31;
    const int hh = h * 16;

    const float* Pb = Pout + (size_t)b * Cz * 1024;
    float al = initial[j];

    float q0[16], q1[16], q2[16], q3[16];
    LOADQ(q0, 0); LOADQ(q1, 1); LOADQ(q2, 2); LOADQ(q3, 3);
    for (int cc = 0; cc < Cz; cc += 4) {
        PROCQ(q0); LOADQ(q0, cc + 4);
        PROCQ(q1); LOADQ(q1, cc + 5);
        PROCQ(q2); LOADQ(q2, cc + 6);
        PROCQ(q3); LOADQ(q3, cc + 7);
    }

    // denom = lse_j(alpha[j]+final[j]); mask dup half, cross-half reduce first
    float mm = (h == 0) ? (al + fin[j]) : -INFINITY;
    float ss = 1.f;
#pragma unroll
    for (int off = 32; off >= 1; off >>= 1) {
        float om = __shfl_xor(mm, off, 64);
        float os = __shfl_xor(ss, off, 64);
        float nm = fmaxf(mm, om);
        ss = ss * __expf(mm - nm) + os * __expf(om - nm);
        mm = nm;
    }
    float denom = mm + __logf(ss);

    float np = numpart[b * Cz + lane];   // Cz == 64 lanes
#pragma unroll
    for (int off = 32; off >= 1; off >>= 1) np += __shfl_xor(np, off, 64);

    if (lane == 0) {
        const int* tg = targets + b * (Tz + 1);
        out[b] = np + initial[tg[0]] + fin[tg[Tz]] - denom;
    }
}

extern "C" void kernel_launch(void* const* d_in, const int* in_sizes, int n_in,
                              void* d_out, int out_size, void* d_ws, size_t ws_size,
                              hipStream_t stream) {
    const float* inputs  = (const float*)d_in[0];
    const float* trans   = (const float*)d_in[1];
    const float* initial = (const float*)d_in[2];
    const float* fin     = (const float*)d_in[3];
    const int*   targets = (const int*)d_in[4];

    float* Pout    = (float*)d_ws;                       // 2048*1024 fp32 = 8 MB
    float* numpart = Pout + (size_t)Bz * Cz * 1024;      // + 8 KB

    hipLaunchKernelGGL(crf_chunks, dim3(Bz * Cz / WPB), dim3(256), 0, stream,
                       inputs, trans, targets, Pout, numpart);
    hipLaunchKernelGGL(crf_combine, dim3(Bz), dim3(64), 0, stream,
                       Pout, numpart, initial, fin, targets, (float*)d_out);
}

// Round 12
// 396.374 us; speedup vs baseline: 1.2276x; 1.0094x over previous
//
#include <hip/hip_runtime.h>
#include <cmath>

#define Bz 32
#define Tz 2048
#define Vz 32
#define Cz 64   // chunks per batch
#define Lz 32   // steps per chunk
#define WPB 4   // waves (chunks) per block

typedef short short8 __attribute__((ext_vector_type(8)));
typedef float f32x16 __attribute__((ext_vector_type(16)));
typedef unsigned int u32x4 __attribute__((ext_vector_type(4)));

#define D0 4.0f              // fixed log-shift (wave-uniform, no per-step reduction)
#define LOG2E 1.4426950408889634f
#define NEGBIG (-1.0e30f)    // finite stand-in for -inf: keeps every lse NaN-free

static __device__ __forceinline__ unsigned cvtpk(float lo, float hi) {
    unsigned r;
    asm("v_cvt_pk_bf16_f32 %0, %1, %2" : "=v"(r) : "v"(lo), "v"(hi));
    return r;
}

// tree max of 16 (dep depth 4)
#define WMAX16(dst, arr) do {                                               \
    float w0=fmaxf(arr[0],arr[1]),  w1=fmaxf(arr[2],arr[3]);                \
    float w2=fmaxf(arr[4],arr[5]),  w3=fmaxf(arr[6],arr[7]);                \
    float w4=fmaxf(arr[8],arr[9]),  w5=fmaxf(arr[10],arr[11]);              \
    float w6=fmaxf(arr[12],arr[13]),w7=fmaxf(arr[14],arr[15]);              \
    w0=fmaxf(w0,w1); w2=fmaxf(w2,w3); w4=fmaxf(w4,w5); w6=fmaxf(w6,w7);     \
    w0=fmaxf(w0,w2); w4=fmaxf(w4,w6); dst = fmaxf(w0,w4);                   \
} while (0)

#define WAVEMAXF(v) do {                                                    \
    v = fmaxf(v, __shfl_xor(v, 1, 64));                                     \
    v = fmaxf(v, __shfl_xor(v, 2, 64));                                     \
    v = fmaxf(v, __shfl_xor(v, 4, 64));                                     \
    v = fmaxf(v, __shfl_xor(v, 8, 64));                                     \
    v = fmaxf(v, __shfl_xor(v, 16, 64));                                    \
    v = fmaxf(v, __shfl_xor(v, 32, 64));                                    \
} while (0)

// ---------------- Kernel A: per-(batch,chunk) semiring product, all-register ----------------
// State S = E^T in MFMA C-layout regs (f32x16 p). Fixed shift D0 (no per-step
// reduction): A-frag = exp2((s+tr-D0)*log2e) — one fma + v_exp per elem.
// Renorm (wave-max scale) every 4 steps (round-9-proven cadence). B-frag of S
// from p: cvt_pk pack, shfl_xor(32), static selects per inverse C-layout
// (C/D layout HW-verified m74/m101; k-slot bijection cancels between A and B).
// NaN-proofing: Pc clamped to >= NEGBIG (no -inf leaves this kernel); ms guarded.
__global__ void __launch_bounds__(256, 2) crf_chunks(
    const float* __restrict__ inputs, const float* __restrict__ trans,
    const int* __restrict__ targets, float* __restrict__ Pout,
    float* __restrict__ numpart)
{
    __shared__ __align__(16) float trans_lds[1024];

    const int tid  = threadIdx.x;
    const int lane = tid & 63;
    const int wid  = tid >> 6;
    const int gid  = blockIdx.x * WPB + wid;
    const int b    = gid >> 6;          // / Cz
    const int c    = gid & (Cz - 1);

    const int H   = lane >> 5;
    const int col = lane & 31;          // A row / B col / C col
    const int kb1 = 8 * H;
    const int kb2 = 16 + 8 * H;

    // (trans - D0) * log2e at this lane's 16 (k,col) fragment slots
    float tr[16];
#pragma unroll
    for (int e = 0; e < 8; ++e) {
        tr[e]     = (trans[(kb1 + e) * Vz + col] - D0) * LOG2E;
        tr[8 + e] = (trans[(kb2 + e) * Vz + col] - D0) * LOG2E;
    }
    ((float4*)trans_lds)[tid] = ((const float4*)trans)[tid];
    __syncthreads();

    const float* src = inputs + ((size_t)b * Tz + (size_t)c * Lz) * 1024;

    // numerator: lane t<32 owns step t (fully parallel, off the critical path)
    const int* tgb = targets + b * (Tz + 1) + c * Lz;
    int tg  = (lane <= Lz) ? tgb[lane] : 0;
    int tgn = __shfl(tg, lane + 1, 64);
    float epart = 0.f;
    if (lane < Lz) {
        int eidx = tg * Vz + tgn;
        epart = src[lane * 1024 + eidx] + trans_lds[eidx];
    }

    // S = I in C-layout
    f32x16 p;
#pragma unroll
    for (int r = 0; r < 16; ++r)
        p[r] = (((r & 3) + 8 * (r >> 2) + 4 * H) == col) ? 1.f : 0.f;
    float gam = Lz * D0;    // Sigma of the fixed per-step shifts

#define LOADM(buf, t) do {                                                  \
    const float* s_ = src + (size_t)(t) * 1024;                             \
    _Pragma("unroll")                                                       \
    for (int e = 0; e < 8; ++e) {                                           \
        buf[e]     = s_[(kb1 + e) * Vz + col];                              \
        buf[8 + e] = s_[(kb2 + e) * Vz + col];                              \
    } } while (0)

    float mA[16], mB[16], mC[16], mD[16];
    LOADM(mA, 0); LOADM(mB, 1); LOADM(mC, 2); LOADM(mD, 3);

#define STEP(buf, t, RN) do {                                               \
    float x[16];                                                            \
    _Pragma("unroll")                                                       \
    for (int i_ = 0; i_ < 16; ++i_) x[i_] = fmaf(buf[i_], LOG2E, tr[i_]);   \
    if ((t) + 4 < Lz) LOADM(buf, (t) + 4);   /* depth-4 reg prefetch */     \
    /* A-frags: exp2(x) + cvt_pk — no reduction, off the p-critical-path */ \
    float ax[16];                                                           \
    _Pragma("unroll")                                                       \
    for (int i_ = 0; i_ < 16; ++i_) ax[i_] = exp2f(x[i_]);                  \
    u32x4 a1u, a2u;                                                         \
    _Pragma("unroll")                                                       \
    for (int e = 0; e < 4; ++e) {                                           \
        a1u[e] = cvtpk(ax[2*e],   ax[2*e+1]);                               \
        a2u[e] = cvtpk(ax[8+2*e], ax[8+2*e+1]);                             \
    }                                                                       \
    /* B-frags from S: cvt_pk pack, cross-half swap, static select */       \
    unsigned pk[8], qk[8];                                                  \
    _Pragma("unroll")                                                       \
    for (int i_ = 0; i_ < 8; ++i_) pk[i_] = cvtpk(p[2*i_], p[2*i_+1]);      \
    _Pragma("unroll")                                                       \
    for (int i_ = 0; i_ < 8; ++i_) qk[i_] = __shfl_xor(pk[i_], 32, 64);     \
    u32x4 b1u, b2u;                                                         \
    b1u[0] = H ? qk[2] : pk[0];  b1u[1] = H ? qk[3] : pk[1];                \
    b1u[2] = H ? pk[2] : qk[0];  b1u[3] = H ? pk[3] : qk[1];                \
    b2u[0] = H ? qk[6] : pk[4];  b2u[1] = H ? qk[7] : pk[5];                \
    b2u[2] = H ? pk[6] : qk[4];  b2u[3] = H ? pk[7] : qk[5];                \
    short8 A1 = __builtin_bit_cast(short8, a1u);                            \
    short8 A2 = __builtin_bit_cast(short8, a2u);                            \
    short8 B1 = __builtin_bit_cast(short8, b1u);                            \
    short8 B2 = __builtin_bit_cast(short8, b2u);                            \
    f32x16 z = {};                                                          \
    p = __builtin_amdgcn_mfma_f32_32x32x16_bf16(A1, B1, z, 0, 0, 0);        \
    p = __builtin_amdgcn_mfma_f32_32x32x16_bf16(A2, B2, p, 0, 0, 0);        \
    if (RN) {   /* renorm every 4th step; guarded against ms==0 */          \
        float ms; WMAX16(ms, p); WAVEMAXF(ms);                              \
        ms = fmaxf(ms, 1e-30f);                                             \
        float inv = 1.0f / ms;                                              \
        _Pragma("unroll")                                                   \
        for (int r_ = 0; r_ < 16; ++r_) p[r_] *= inv;                       \
        gam += __logf(ms);                                                  \
    }                                                                       \
} while (0)

#pragma unroll 1
    for (int t = 0; t < Lz; t += 8) {   // rolled: cap I-cache footprint
        STEP(mA, t,     0); STEP(mB, t + 1, 0);
        STEP(mC, t + 2, 0); STEP(mD, t + 3, 1);
        STEP(mA, t + 4, 0); STEP(mB, t + 5, 0);
        STEP(mC, t + 6, 0); STEP(mD, t + 7, 1);
    }

    // Pc = gam + log S, clamped finite (no -inf ever enters Pout)
    float* Pc = Pout + (size_t)gid * 1024;
#pragma unroll
    for (int r = 0; r < 16; ++r) {
        int row = (r & 3) + 8 * (r >> 2) + 4 * H;
        Pc[row * Vz + col] = fmaxf(gam + __logf(p[r]), NEGBIG);
    }
#pragma unroll
    for (int off = 32; off >= 1; off >>= 1) epart += __shfl_xor(epart, off, 64);
    if (lane == 0) numpart[gid] = epart;
}

// ---------------- Kernel B: sequential combine (1 wave/batch) ----------------
// All inputs finite (chunks clamps at source) -> every reduce NaN-free.
#define LOADQ(buf, chunk) do { if ((chunk) < Cz) {                          \
    const float4* Pn = (const float4*)(Pb + (size_t)(chunk) * 1024 + j * 32 + hh); \
    float4 v0 = Pn[0], v1 = Pn[1], v2 = Pn[2], v3 = Pn[3];                  \
    buf[0]=v0.x; buf[1]=v0.y; buf[2]=v0.z; buf[3]=v0.w;                     \
    buf[4]=v1.x; buf[5]=v1.y; buf[6]=v1.z; buf[7]=v1.w;                     \
    buf[8]=v2.x; buf[9]=v2.y; buf[10]=v2.z; buf[11]=v2.w;                   \
    buf[12]=v3.x; buf[13]=v3.y; buf[14]=v3.z; buf[15]=v3.w;                 \
} } while (0)

#define PROCQ(buf) do {                                                     \
    float x[16];                                                            \
    _Pragma("unroll")                                                       \
    for (int ii = 0; ii < 16; ++ii)                                         \
        x[ii] = __shfl(al, hh + ii, 64) + buf[ii];                          \
    float mx; WMAX16(mx, x);                                                \
    mx = fmaxf(mx, __shfl_xor(mx, 32, 64));                                 \
    float e[16];                                                            \
    _Pragma("unroll")                                                       \
    for (int ii = 0; ii < 16; ++ii) e[ii] = __expf(x[ii] - mx);             \
    float s0=e[0]+e[1],   s1=e[2]+e[3],   s2=e[4]+e[5],   s3=e[6]+e[7];     \
    float s4=e[8]+e[9],   s5=e[10]+e[11], s6=e[12]+e[13], s7=e[14]+e[15];   \
    s0+=s1; s2+=s3; s4+=s5; s6+=s7; s0+=s2; s4+=s6;                         \
    float s = s0 + s4;                                                      \
    s += __shfl_xor(s, 32, 64);                                             \
    al = mx + __logf(s);                                                    \
} while (0)

__global__ void __launch_bounds__(64) crf_combine(
    const float* __restrict__ Pout, const float* __restrict__ numpart,
    const float* __restrict__ initial, const float* __restrict__ fin,
    const int* __restrict__ targets, float* __restrict__ out)
{
    const int lane = threadIdx.x;
    const int b = blockIdx.x;
    const int h = lane >> 5;
    const int j = lane & 31;
    const int hh = h * 16;

    const float* Pb = Pout + (size_t)b * Cz * 1024;
    float al = initial[j];

    float q0[16], q1[16], q2[16], q3[16];
    LOADQ(q0, 0); LOADQ(q1, 1); LOADQ(q2, 2); LOADQ(q3, 3);
    for (int cc = 0; cc < Cz; cc += 4) {
        PROCQ(q0); LOADQ(q0, cc + 4);
        PROCQ(q1); LOADQ(q1, cc + 5);
        PROCQ(q2); LOADQ(q2, cc + 6);
        PROCQ(q3); LOADQ(q3, cc + 7);
    }

    // denom = lse_j(alpha[j]+final[j]); dup half masked with finite NEGBIG
    float mm = (h == 0) ? (al + fin[j]) : NEGBIG;
    float ss = 1.f;
#pragma unroll
    for (int off = 32; off >= 1; off >>= 1) {
        float om = __shfl_xor(mm, off, 64);
        float os = __shfl_xor(ss, off, 64);
        float nm = fmaxf(mm, om);
        ss = ss * __expf(mm - nm) + os * __expf(om - nm);
        mm = nm;
    }
    float denom = mm + __logf(ss);

    float np = numpart[b * Cz + lane];   // Cz == 64 lanes
#pragma unroll
    for (int off = 32; off >= 1; off >>= 1) np += __shfl_xor(np, off, 64);

    if (lane == 0) {
        const int* tg = targets + b * (Tz + 1);
        out[b] = np + initial[tg[0]] + fin[tg[Tz]] - denom;
    }
}

extern "C" void kernel_launch(void* const* d_in, const int* in_sizes, int n_in,
                              void* d_out, int out_size, void* d_ws, size_t ws_size,
                              hipStream_t stream) {
    const float* inputs  = (const float*)d_in[0];
    const float* trans   = (const float*)d_in[1];
    const float* initial = (const float*)d_in[2];
    const float* fin     = (const float*)d_in[3];
    const int*   targets = (const int*)d_in[4];

    float* Pout    = (float*)d_ws;                       // 2048*1024 fp32 = 8 MB
    float* numpart = Pout + (size_t)Bz * Cz * 1024;      // + 8 KB

    hipLaunchKernelGGL(crf_chunks, dim3(Bz * Cz / WPB), dim3(256), 0, stream,
                       inputs, trans, targets, Pout, numpart);
    hipLaunchKernelGGL(crf_combine, dim3(Bz), dim3(64), 0, stream,
                       Pout, numpart, initial, fin, targets, (float*)d_out);
}